// Round 6
// baseline (745.147 us; speedup 1.0000x reference)
//
#include <hip/hip_runtime.h>
#include <hip/hip_cooperative_groups.h>
#include <math.h>

namespace cg = cooperative_groups;

#define INV_TAU   20.0f
#define LOGN      6.931471805599453f   // log(1024)
#define B1        0.9f
#define B2        0.999f
#define EPS_ADAM  1e-8f

constexpr int BATCH = 8;
constexpr int N = 1024;
constexpr int M = 1024;
constexpr int NITER = 10;

// ---------- persistent (cooperative) config ----------
constexpr int P_RPB  = 32;               // rows per block
constexpr int P_NCH  = N / P_RPB;        // 32 chunks per batch
constexpr int P_NBLK = BATCH * P_NCH;    // 256 blocks = 1 per CU (trivially co-resident)
constexpr int P_NTHR = 512;

__device__ inline float wave_max64(float x) {
#pragma unroll
  for (int off = 1; off < 64; off <<= 1) x = fmaxf(x, __shfl_xor(x, off));
  return x;
}
__device__ inline float wave_sum64(float x) {
#pragma unroll
  for (int off = 1; off < 64; off <<= 1) x += __shfl_xor(x, off);
  return x;
}
__device__ inline float2 lse_merge(float2 a, float2 b) {
  float m = fmaxf(a.x, b.x);
  float s = a.y * __expf(a.x - m) + b.y * __expf(b.x - m);
  return make_float2(m, s);
}

// One persistent kernel: 256 blocks x 512 threads, ~17 KB LDS, matrix column-slices
// held in registers (16 x float4 per thread). grid.sync() twice per iteration.
__global__ __launch_bounds__(P_NTHR, 2) void k_sink(
    const float* __restrict__ la, float* __restrict__ out,
    float* __restrict__ vg, float* __restrict__ pm, float* __restrict__ ps)
{
  cg::grid_group grid = cg::this_grid();

  __shared__ float4 cmm4[256], css4[256];            // 8 KB: col-pass half-merge
  __shared__ float u_s[P_RPB], mu_s[P_RPB], vu_s[P_RPB];
  __shared__ float vst[P_RPB], mv_s[P_RPB], vv_s[P_RPB];

  const int blk = blockIdx.x;
  const int b   = blk & 7;         // batch -> XCD-local under bid%8 mapping
  const int c   = blk >> 3;        // row chunk 0..31
  const int i0  = c * P_RPB;
  const int tid = threadIdx.x;

  const float4* la4 = (const float4*)la;
  const float4* vg4 = (const float4*)(vg + b * M);

  const int c4 = tid & 255;        // column float4 index (col layout)
  const int rg = tid >> 8;         // row half: 0 -> rows 0..15, 1 -> rows 16..31
  const int w    = tid >> 6;       // wave 0..7 (row layout)
  const int lane = tid & 63;

  // ---- prologue: pull my 16-row column slice into registers (scaled by 1/tau) ----
  float4 y[16];
#pragma unroll
  for (int rr = 0; rr < 16; ++rr) {
    float4 t = la4[((size_t)(b * N + i0 + (rg << 4) + rr) << 8) + c4];
    t.x *= INV_TAU; t.y *= INV_TAU; t.z *= INV_TAU; t.w *= INV_TAU;
    y[rr] = t;
  }
  if (tid < P_RPB) {
    u_s[tid] = 0.f; mu_s[tid] = 0.f; vu_s[tid] = 0.f;
    vst[tid] = 0.f; mv_s[tid] = 0.f; vv_s[tid] = 0.f;
  }
  __syncthreads();

  float p1 = 1.0f, p2 = 1.0f;

  for (int it = 0; it < NITER; ++it) {
    p1 *= B1; p2 *= B2;
    const float bc1 = 1.0f - p1, bc2 = 1.0f - p2;

    // ---- u half-step: wave-per-row, rows re-read from L2 (row-major) ----
    for (int s = 0; s < 4; ++s) {
      const int r = (w << 2) | s;                       // 0..31
      const float4* rowp = la4 + ((size_t)(b * N + i0 + r) << 8);
      float x[16];
      float mx = -INFINITY;
#pragma unroll
      for (int tq = 0; tq < 4; ++tq) {
        float4 k4 = rowp[lane + (tq << 6)];
        float4 v4 = make_float4(0.f, 0.f, 0.f, 0.f);
        if (it != 0) v4 = vg4[lane + (tq << 6)];
        x[4*tq+0] = fmaf(k4.x, INV_TAU, v4.x);
        x[4*tq+1] = fmaf(k4.y, INV_TAU, v4.y);
        x[4*tq+2] = fmaf(k4.z, INV_TAU, v4.z);
        x[4*tq+3] = fmaf(k4.w, INV_TAU, v4.w);
        mx = fmaxf(mx, fmaxf(fmaxf(x[4*tq+0], x[4*tq+1]), fmaxf(x[4*tq+2], x[4*tq+3])));
      }
      mx = wave_max64(mx);
      float ss = 0.f;
#pragma unroll
      for (int q = 0; q < 16; ++q) ss += __expf(x[q] - mx);
      ss = wave_sum64(ss);
      if (lane == 0) {
        float lse = mx + __logf(ss);
        float g   = (-LOGN - lse) - u_s[r];
        float mn  = B1 * mu_s[r] + (1.0f - B1) * g;
        float vn  = B2 * vu_s[r] + (1.0f - B2) * g * g;
        mu_s[r] = mn; vu_s[r] = vn;
        u_s[r]  = u_s[r] + (mn / bc1) / (sqrtf(vn / bc2) + EPS_ADAM);
      }
    }
    __syncthreads();   // u_s ready for col pass

    // ---- column partials from registers (two-pass, 1 exp/elem, no re-read) ----
    {
      float4 xm = make_float4(-INFINITY, -INFINITY, -INFINITY, -INFINITY);
#pragma unroll
      for (int rr = 0; rr < 16; ++rr) {
        float uu = u_s[(rg << 4) + rr];
        xm.x = fmaxf(xm.x, y[rr].x + uu); xm.y = fmaxf(xm.y, y[rr].y + uu);
        xm.z = fmaxf(xm.z, y[rr].z + uu); xm.w = fmaxf(xm.w, y[rr].w + uu);
      }
      float4 xs = make_float4(0.f, 0.f, 0.f, 0.f);
#pragma unroll
      for (int rr = 0; rr < 16; ++rr) {
        float uu = u_s[(rg << 4) + rr];
        xs.x += __expf(y[rr].x + uu - xm.x); xs.y += __expf(y[rr].y + uu - xm.y);
        xs.z += __expf(y[rr].z + uu - xm.z); xs.w += __expf(y[rr].w + uu - xm.w);
      }
      if (rg == 1) { cmm4[c4] = xm; css4[c4] = xs; }
      __syncthreads();
      if (rg == 0) {
        float4 om = cmm4[c4], os = css4[c4];
        float4 nm, ns;
        nm.x = fmaxf(xm.x, om.x); ns.x = xs.x * __expf(xm.x - nm.x) + os.x * __expf(om.x - nm.x);
        nm.y = fmaxf(xm.y, om.y); ns.y = xs.y * __expf(xm.y - nm.y) + os.y * __expf(om.y - nm.y);
        nm.z = fmaxf(xm.z, om.z); ns.z = xs.z * __expf(xm.z - nm.z) + os.z * __expf(om.z - nm.z);
        nm.w = fmaxf(xm.w, om.w); ns.w = xs.w * __expf(xm.w - nm.w) + os.w * __expf(om.w - nm.w);
        ((float4*)(pm + c * (BATCH * M) + b * M))[c4] = nm;
        ((float4*)(ps + c * (BATCH * M) + b * M))[c4] = ns;
      }
    }
    grid.sync();   // partials visible

    // ---- combine 32 chunk-partials + v Adam (32 owned entries x 16 lanes) ----
    {
      const int g2  = tid >> 4;          // 0..31
      const int l16 = tid & 15;
      const int j   = i0 + g2;
      const float* pmp = pm + b * M + j;
      const float* psp = ps + b * M + j;
      float2 acc = make_float2(pmp[(size_t)l16 * (BATCH * M)],
                               psp[(size_t)l16 * (BATCH * M)]);
      float2 o2  = make_float2(pmp[(size_t)(l16 + 16) * (BATCH * M)],
                               psp[(size_t)(l16 + 16) * (BATCH * M)]);
      acc = lse_merge(acc, o2);
#pragma unroll
      for (int off = 1; off < 16; off <<= 1) {
        float om  = __shfl_xor(acc.x, off, 16);
        float osv = __shfl_xor(acc.y, off, 16);
        acc = lse_merge(acc, make_float2(om, osv));
      }
      if (l16 == 0) {
        float lse = acc.x + __logf(acc.y);
        float gv  = (-LOGN - lse) - vst[g2];
        float mn  = B1 * mv_s[g2] + (1.0f - B1) * gv;
        float vn  = B2 * vv_s[g2] + (1.0f - B2) * gv * gv;
        mv_s[g2] = mn; vv_s[g2] = vn;
        float vnew = vst[g2] + (mn / bc1) / (sqrtf(vn / bc2) + EPS_ADAM);
        vst[g2] = vnew;
        vg[b * M + j] = vnew;
      }
    }
    grid.sync();   // v visible for next u-step
  }

  // ---- plan epilogue straight from registers ----
  {
    float4 vv4 = vg4[c4];
    float4* out4 = (float4*)out;
#pragma unroll
    for (int rr = 0; rr < 16; ++rr) {
      float uu = u_s[(rg << 4) + rr];
      float4 o;
      o.x = __expf(y[rr].x + uu + vv4.x);
      o.y = __expf(y[rr].y + uu + vv4.y);
      o.z = __expf(y[rr].z + uu + vv4.z);
      o.w = __expf(y[rr].w + uu + vv4.w);
      out4[((size_t)(b * N + i0 + (rg << 4) + rr) << 8) + c4] = o;
    }
  }
}

// ================= fallback: round-2 multi-kernel path (proven, 275 us) =================
constexpr int F_NCHUNK = 32;
constexpr int F_RPC    = N / F_NCHUNK;   // 32

__global__ __launch_bounds__(256) void k_init(float* __restrict__ ws) {
  int i = blockIdx.x * 256 + threadIdx.x;
  ws[i] = 0.0f;
}

__global__ __launch_bounds__(256) void k_row_u(
    const float* __restrict__ la, const float* __restrict__ v,
    float* __restrict__ u, float* __restrict__ mu, float* __restrict__ vu,
    float bc1, float bc2)
{
  int gw   = (blockIdx.x << 2) + (threadIdx.x >> 6);
  int lane = threadIdx.x & 63;
  int b = gw >> 10;
  const float4* rowp = (const float4*)(la + (size_t)gw * M);
  const float4* vp   = (const float4*)(v + b * M);

  float x[16];
  float m = -INFINITY;
#pragma unroll
  for (int t = 0; t < 4; ++t) {
    float4 k4 = rowp[lane + 64 * t];
    float4 v4 = vp[lane + 64 * t];
    x[4*t+0] = fmaf(k4.x, INV_TAU, v4.x);
    x[4*t+1] = fmaf(k4.y, INV_TAU, v4.y);
    x[4*t+2] = fmaf(k4.z, INV_TAU, v4.z);
    x[4*t+3] = fmaf(k4.w, INV_TAU, v4.w);
    m = fmaxf(m, fmaxf(fmaxf(x[4*t+0], x[4*t+1]), fmaxf(x[4*t+2], x[4*t+3])));
  }
  m = wave_max64(m);
  float s = 0.0f;
#pragma unroll
  for (int t = 0; t < 16; ++t) s += __expf(x[t] - m);
  s = wave_sum64(s);

  if (lane == 0) {
    float lse = m + __logf(s);
    float g   = (-LOGN - lse) - u[gw];
    float mn  = B1 * mu[gw] + (1.0f - B1) * g;
    float vn  = B2 * vu[gw] + (1.0f - B2) * g * g;
    mu[gw] = mn;
    vu[gw] = vn;
    u[gw]  = u[gw] + (mn / bc1) / (sqrtf(vn / bc2) + EPS_ADAM);
  }
}

__global__ __launch_bounds__(256) void k_col_partial(
    const float* __restrict__ la, const float* __restrict__ u,
    float* __restrict__ pm, float* __restrict__ ps)
{
  int b  = blockIdx.x >> 5;
  int cn = blockIdx.x & 31;
  int tid = threadIdx.x;
  int i0 = cn * F_RPC;

  __shared__ float su[F_RPC];
  if (tid < F_RPC) su[tid] = u[b * N + i0 + tid];
  __syncthreads();

  const float4* base = (const float4*)(la + (size_t)(b * N + i0) * M);
  float4 m = make_float4(-INFINITY, -INFINITY, -INFINITY, -INFINITY);
  float4 s = make_float4(0.f, 0.f, 0.f, 0.f);

#pragma unroll 4
  for (int i = 0; i < F_RPC; ++i) {
    float uu = su[i];
    float4 k4 = base[i * 256 + tid];
    float x, nm;
    x = fmaf(k4.x, INV_TAU, uu); nm = fmaxf(m.x, x);
    s.x = s.x * __expf(m.x - nm) + __expf(x - nm); m.x = nm;
    x = fmaf(k4.y, INV_TAU, uu); nm = fmaxf(m.y, x);
    s.y = s.y * __expf(m.y - nm) + __expf(x - nm); m.y = nm;
    x = fmaf(k4.z, INV_TAU, uu); nm = fmaxf(m.z, x);
    s.z = s.z * __expf(m.z - nm) + __expf(x - nm); m.z = nm;
    x = fmaf(k4.w, INV_TAU, uu); nm = fmaxf(m.w, x);
    s.w = s.w * __expf(m.w - nm) + __expf(x - nm); m.w = nm;
  }

  int off = cn * (BATCH * M) + b * M;
  ((float4*)(pm + off))[tid] = m;
  ((float4*)(ps + off))[tid] = s;
}

__global__ __launch_bounds__(256) void k_combine_v(
    const float* __restrict__ pm, const float* __restrict__ ps,
    float* __restrict__ v, float* __restrict__ mv, float* __restrict__ vv,
    float bc1, float bc2)
{
  int c = blockIdx.x * 256 + threadIdx.x;
  float Mx = -INFINITY, S = 0.0f;
#pragma unroll
  for (int cn = 0; cn < F_NCHUNK; ++cn) {
    float m = pm[cn * (BATCH * M) + c];
    float s = ps[cn * (BATCH * M) + c];
    float nM = fmaxf(Mx, m);
    S = S * __expf(Mx - nM) + s * __expf(m - nM);
    Mx = nM;
  }
  float lse = Mx + __logf(S);
  float g  = (-LOGN - lse) - v[c];
  float mn = B1 * mv[c] + (1.0f - B1) * g;
  float vn = B2 * vv[c] + (1.0f - B2) * g * g;
  mv[c] = mn;
  vv[c] = vn;
  v[c]  = v[c] + (mn / bc1) / (sqrtf(vn / bc2) + EPS_ADAM);
}

__global__ __launch_bounds__(256) void k_plan(
    const float* __restrict__ la, const float* __restrict__ u,
    const float* __restrict__ v, float* __restrict__ out)
{
  size_t idx = (size_t)blockIdx.x * 256 + threadIdx.x;
  int row = (int)(idx >> 8);
  int b   = row >> 10;
  int jc  = (int)(idx & 255);
  float ur  = u[row];
  float4 v4 = ((const float4*)(v + b * M))[jc];
  float4 k4 = ((const float4*)la)[idx];
  float4 o;
  o.x = __expf(fmaf(k4.x, INV_TAU, ur + v4.x));
  o.y = __expf(fmaf(k4.y, INV_TAU, ur + v4.y));
  o.z = __expf(fmaf(k4.z, INV_TAU, ur + v4.z));
  o.w = __expf(fmaf(k4.w, INV_TAU, ur + v4.w));
  ((float4*)out)[idx] = o;
}

extern "C" void kernel_launch(void* const* d_in, const int* in_sizes, int n_in,
                              void* d_out, int out_size, void* d_ws, size_t ws_size,
                              hipStream_t stream) {
  const float* la = (const float*)d_in[0];
  float* out = (float*)d_out;
  float* ws  = (float*)d_ws;

  // persistent-path ws layout
  float* vg = ws;                          // [8][1024]
  float* pm = ws + BATCH * M;              // [32][8][1024]
  float* ps = pm + P_NCH * BATCH * M;      // [32][8][1024]

  void* args[] = { (void*)&la, (void*)&out, (void*)&vg, (void*)&pm, (void*)&ps };
  hipError_t err = hipLaunchCooperativeKernel((const void*)k_sink,
                                              dim3(P_NBLK), dim3(P_NTHR),
                                              args, 0, stream);
  if (err != hipSuccess) {
    // fallback: proven multi-kernel path (round 2), its own ws layout
    float* u   = ws;
    float* v   = ws + 8192;
    float* mu  = ws + 16384;
    float* vu  = ws + 24576;
    float* mv  = ws + 32768;
    float* vv  = ws + 40960;
    float* pm2 = ws + 49152;
    float* ps2 = pm2 + F_NCHUNK * BATCH * M;

    k_init<<<192, 256, 0, stream>>>(ws);
    for (int it = 0; it < NITER; ++it) {
      float t = (float)(it + 1);
      float bc1 = 1.0f - powf(B1, t);
      float bc2 = 1.0f - powf(B2, t);
      k_row_u<<<(BATCH * N) / 4, 256, 0, stream>>>(la, v, u, mu, vu, bc1, bc2);
      k_col_partial<<<BATCH * F_NCHUNK, 256, 0, stream>>>(la, u, pm2, ps2);
      k_combine_v<<<(BATCH * M) / 256, 256, 0, stream>>>(pm2, ps2, v, mv, vv, bc1, bc2);
    }
    k_plan<<<(BATCH * N * M) / 4 / 256, 256, 0, stream>>>(la, u, v, out);
  }
}